// Round 4
// baseline (261.656 us; speedup 1.0000x reference)
//
#include <hip/hip_runtime.h>
#include <hip/hip_bf16.h>

// QDense: out = s * (U X U^H)[:128,:128] / tr + (1-s) * diag(softmax(rand_w))
// B=512, D=256, O=128.
// 1024 blocks (batch b = bx>>1, k'-half kh = bx&1), 512 thr.
// U and Q=P^T are pre-packed in MFMA-fragment order in global memory:
//   frag(g, s) = rows g*16..+16, k = s*32..+32; lane (c16,g4) holds
//   row g*16+c16, k = s*32+g4*8 .. +8  ->  addr ((g*8+s)*64 + lane)*8 shorts.
// Stage A: Y[j, k'half] = X * U_half^H   (U frags from global, L2-hot)
// Stage B: sub[:, k'half] = U_sub * Y    (Y^T in double-buffered swizzled LDS)
// Trace:   tr = trace(X * P) folded into stage A on waves 0..3.

typedef __attribute__((ext_vector_type(4))) float f32x4;
typedef __attribute__((ext_vector_type(8))) short bf16x8;

static __device__ __forceinline__ short f2bf(float f) {   // prep kernels only
    unsigned u = __float_as_uint(f);
    u += 0x7fffu + ((u >> 16) & 1u);
    return (short)(u >> 16);
}

static __device__ __forceinline__ unsigned cvtpk2(float lo, float hi) {
    union { __hip_bfloat162 h; unsigned u; } c;
    c.h = __float22bfloat162_rn(float2{lo, hi});
    return c.u;
}

static __device__ __forceinline__ bf16x8 pack8(f32x4 a, f32x4 b) {
    union { unsigned u[4]; bf16x8 v; } r;
    r.u[0] = cvtpk2(a[0], a[1]);
    r.u[1] = cvtpk2(a[2], a[3]);
    r.u[2] = cvtpk2(b[0], b[1]);
    r.u[3] = cvtpk2(b[2], b[3]);
    return r.v;
}

static __device__ __forceinline__ f32x4 mfma16(bf16x8 a, bf16x8 b, f32x4 c) {
    return __builtin_amdgcn_mfma_f32_16x16x32_bf16(a, b, c, 0, 0, 0);
}

// ---- prep: U rows [0,128) -> bf16, fragment-packed ----
__global__ void qprep_u(const float* __restrict__ wt,
                        short* __restrict__ Upr, short* __restrict__ Upi) {
    int idx = blockIdx.x * 256 + threadIdx.x;     // j*256+k, j<128
    int j = idx >> 8, k = idx & 255;
    float2 v = ((const float2*)wt)[idx];
    int g = j >> 4, s = k >> 5;
    int lanep = (j & 15) | (((k >> 3) & 3) << 4);
    int p = ((g * 8 + s) * 64 + lanep) * 8 + (k & 7);
    Upr[p] = f2bf(v.x);
    Upi[p] = f2bf(v.y);
}

// ---- prep: p = softmax(rand_w), s = sigmoid(lam) ----
__global__ void qprep_ps(const float* __restrict__ rw, const float* __restrict__ lm,
                         float* __restrict__ pv, float* __restrict__ sv) {
    int t = threadIdx.x;
    float w0 = rw[t], w1 = rw[t + 64];
    float m = fmaxf(w0, w1);
    #pragma unroll
    for (int o = 32; o > 0; o >>= 1) m = fmaxf(m, __shfl_xor(m, o));
    float e0 = expf(w0 - m), e1 = expf(w1 - m);
    float ss = e0 + e1;
    #pragma unroll
    for (int o = 32; o > 0; o >>= 1) ss += __shfl_xor(ss, o);
    pv[t] = e0 / ss;
    pv[t + 64] = e1 / ss;
    if (t == 0) sv[0] = 1.f / (1.f + expf(-lm[0]));
}

// ---- prep: Q[j][k] = P[k][j], P = U_sub^H U_sub, fragment-packed ----
__global__ void qprep_q(const float* __restrict__ wt,
                        short* __restrict__ Qpr, short* __restrict__ Qpi) {
    int j = blockIdx.x;          // 0..255
    int k = threadIdx.x;         // 0..255
    float ar = 0.f, ai = 0.f;
    for (int i = 0; i < 128; ++i) {
        float2 uk = ((const float2*)wt)[i * 256 + k];
        float2 uj = ((const float2*)wt)[i * 256 + j];
        ar += uk.x * uj.x + uk.y * uj.y;
        ai += uk.x * uj.y - uk.y * uj.x;
    }
    int g = j >> 4, s = k >> 5;
    int lanep = (j & 15) | (((k >> 3) & 3) << 4);
    int p = ((g * 8 + s) * 64 + lanep) * 8 + (k & 7);
    Qpr[p] = f2bf(ar);
    Qpi[p] = f2bf(ai);
}

// ---- main fused kernel ----
__global__ __launch_bounds__(512, 2) void qfused(
    const float* __restrict__ xr, const float* __restrict__ xi,
    const short* __restrict__ Upr, const short* __restrict__ Upi,
    const short* __restrict__ Qpr, const short* __restrict__ Qpi,
    const float* __restrict__ pv, const float* __restrict__ sv,
    float* __restrict__ out)
{
    // Yt double-buffered: R at buf*8192, I at 16384 + buf*8192.
    // 64 rows (k'loc) x 128 B (64 j), 16B-granular XOR swizzle.
    __shared__ __align__(16) char smem[32768];
    __shared__ float red[8];

    const int bx   = blockIdx.x;
    const int b    = bx >> 1;
    const int kh   = bx & 1;
    const int tid  = threadIdx.x;
    const int lane = tid & 63;
    const int w    = tid >> 6;
    const int c16  = lane & 15;
    const int g4   = lane >> 4;
    const int lane8 = lane * 8;

    const int ja  = (w & 3) * 16;          // stage-A j-group
    const int kgA = kh * 4 + (w >> 2) * 2; // stage-A U frag-group base (+nt)
    const int wm  = w >> 1;                // stage-B i-quarter
    const int wn  = w & 1;                 // stage-B k'-half-of-half
    const bool dotr = (w < 4);

    const float* xrb = xr + ((size_t)b << 16);
    const float* xib = xi + ((size_t)b << 16);

    f32x4 zero = {0.f, 0.f, 0.f, 0.f};
    f32x4 sR[2][2], sI[2][2];
    #pragma unroll
    for (int m = 0; m < 2; ++m)
        #pragma unroll
        for (int n = 0; n < 2; ++n) { sR[m][n] = zero; sI[m][n] = zero; }
    f32x4 tr4 = zero;

    for (int jts = 0; jts < 4; ++jts) {
        const int jt   = jts << 6;
        const int bufo = (jts & 1) << 13;   // 0 / 8192

        // ---------- stage A ----------
        f32x4 yR[2], yI[2];
        yR[0] = zero; yR[1] = zero; yI[0] = zero; yI[1] = zero;

        const int jrow = jt + ja + c16;
        const float* xr_row = xrb + (size_t)jrow * 256 + g4 * 8;
        const float* xi_row = xib + (size_t)jrow * 256 + g4 * 8;
        const short* qbr = Qpr + (((jt >> 4) + (w & 3)) << 12) + lane8;
        const short* qbi = Qpi + (((jt >> 4) + (w & 3)) << 12) + lane8;

        #pragma unroll 2
        for (int ks = 0; ks < 8; ++ks) {
            f32x4 a0 = *(const f32x4*)(xr_row + ks * 32);
            f32x4 a1 = *(const f32x4*)(xr_row + ks * 32 + 4);
            f32x4 b0 = *(const f32x4*)(xi_row + ks * 32);
            f32x4 b1 = *(const f32x4*)(xi_row + ks * 32 + 4);
            bf16x8 axr  = pack8(a0, a1);
            bf16x8 axi  = pack8(b0, b1);
            bf16x8 axrn = axr ^ (short)0x8000;

            #pragma unroll
            for (int nt = 0; nt < 2; ++nt) {
                const int fo = ((((kgA + nt) << 3) + ks) << 9);
                bf16x8 bur = *(const bf16x8*)(Upr + fo + lane8);
                bf16x8 bui = *(const bf16x8*)(Upi + fo + lane8);
                // Yr = Xr Ur^T + Xi Ui^T ; Yi = Xi Ur^T - Xr Ui^T
                yR[nt] = mfma16(axr,  bur, yR[nt]);
                yR[nt] = mfma16(axi,  bui, yR[nt]);
                yI[nt] = mfma16(axi,  bur, yI[nt]);
                yI[nt] = mfma16(axrn, bui, yI[nt]);
            }
            if (dotr) {
                bf16x8 bqr  = *(const bf16x8*)(qbr + (ks << 9));
                bf16x8 bqi  = *(const bf16x8*)(qbi + (ks << 9));
                bf16x8 axin = axi ^ (short)0x8000;
                tr4 = mfma16(axr,  bqr, tr4);
                tr4 = mfma16(axin, bqi, tr4);
            }
        }

        // write Yt[buf] (no barrier needed before: other buffer was in use)
        #pragma unroll
        for (int nt = 0; nt < 2; ++nt) {
            int kloc = (w >> 2) * 32 + nt * 16 + c16;
            int off  = kloc * 128 + ((ja * 2 + g4 * 8) ^ ((kloc & 7) << 4));
            uint2 vr, vi;
            vr.x = cvtpk2(yR[nt][0], yR[nt][1]);
            vr.y = cvtpk2(yR[nt][2], yR[nt][3]);
            vi.x = cvtpk2(yI[nt][0], yI[nt][1]);
            vi.y = cvtpk2(yI[nt][2], yI[nt][3]);
            *(uint2*)(smem + bufo + off)         = vr;
            *(uint2*)(smem + 16384 + bufo + off) = vi;
        }
        __syncthreads();

        // ---------- stage B ----------
        #pragma unroll
        for (int ks2 = 0; ks2 < 2; ++ks2) {
            bf16x8 aur[2], aui[2], auin[2];
            #pragma unroll
            for (int mt = 0; mt < 2; ++mt) {
                const int fo = ((((wm * 2 + mt) << 3) + (jt >> 5) + ks2) << 9);
                aur[mt]  = *(const bf16x8*)(Upr + fo + lane8);
                aui[mt]  = *(const bf16x8*)(Upi + fo + lane8);
                auin[mt] = aui[mt] ^ (short)0x8000;
            }
            #pragma unroll
            for (int nt2 = 0; nt2 < 2; ++nt2) {
                int kloc = wn * 32 + nt2 * 16 + c16;
                int off  = kloc * 128 + ((ks2 * 64 + g4 * 16) ^ ((kloc & 7) << 4));
                bf16x8 byr = *(const bf16x8*)(smem + bufo + off);
                bf16x8 byi = *(const bf16x8*)(smem + 16384 + bufo + off);
                #pragma unroll
                for (int mt = 0; mt < 2; ++mt) {
                    // sub_r = Ur Yr - Ui Yi ; sub_i = Ui Yr + Ur Yi
                    sR[mt][nt2] = mfma16(aur[mt],  byr, sR[mt][nt2]);
                    sR[mt][nt2] = mfma16(auin[mt], byi, sR[mt][nt2]);
                    sI[mt][nt2] = mfma16(aui[mt],  byr, sI[mt][nt2]);
                    sI[mt][nt2] = mfma16(aur[mt],  byi, sI[mt][nt2]);
                }
            }
        }
    }

    // ---------- trace reduce ----------
    float loc = (dotr && ((c16 >> 2) == g4)) ? tr4[c16 & 3] : 0.f;
    #pragma unroll
    for (int o = 32; o > 0; o >>= 1) loc += __shfl_xor(loc, o);
    if (lane == 0) red[w] = loc;
    __syncthreads();
    float tr = red[0] + red[1] + red[2] + red[3] + red[4] + red[5] + red[6] + red[7];

    // ---------- epilogue ----------
    float s     = sv[0];
    float inv   = s / tr;
    float onems = 1.f - s;
    float* outr = out + (size_t)b * 16384;
    float* outi = out + 8388608 + (size_t)b * 16384;

    #pragma unroll
    for (int mt = 0; mt < 2; ++mt)
        #pragma unroll
        for (int nt2 = 0; nt2 < 2; ++nt2) {
            int colc = kh * 64 + wn * 32 + nt2 * 16 + c16;
            #pragma unroll
            for (int r = 0; r < 4; ++r) {
                int row = wm * 32 + mt * 16 + g4 * 4 + r;
                float vr = sR[mt][nt2][r] * inv;
                if (row == colc) vr += onems * pv[row];
                outr[row * 128 + colc] = vr;
                outi[row * 128 + colc] = sI[mt][nt2][r] * inv;
            }
        }
}

extern "C" void kernel_launch(void* const* d_in, const int* in_sizes, int n_in,
                              void* d_out, int out_size, void* d_ws, size_t ws_size,
                              hipStream_t stream) {
    (void)in_sizes; (void)n_in; (void)out_size; (void)ws_size;
    const float* xr = (const float*)d_in[0];
    const float* xi = (const float*)d_in[1];
    const float* wt = (const float*)d_in[2];
    const float* rw = (const float*)d_in[3];
    const float* lm = (const float*)d_in[4];

    short* Upr = (short*)d_ws;                        // 64 KB packed frags
    short* Upi = (short*)((char*)d_ws + 65536);       // 64 KB
    short* Qpr = (short*)((char*)d_ws + 131072);      // 128 KB
    short* Qpi = (short*)((char*)d_ws + 262144);      // 128 KB
    float* pv  = (float*)((char*)d_ws + 393216);      // 128 f32
    float* sv  = pv + 128;                            // 1 f32
    float* o   = (float*)d_out;

    qprep_u<<<dim3(128), dim3(256), 0, stream>>>(wt, Upr, Upi);
    qprep_ps<<<dim3(1), dim3(64), 0, stream>>>(rw, lm, pv, sv);
    qprep_q<<<dim3(256), dim3(256), 0, stream>>>(wt, Qpr, Qpi);
    qfused<<<dim3(1024), dim3(512), 0, stream>>>(xr, xi, Upr, Upi, Qpr, Qpi, pv, sv, o);
}

// Round 5
// 212.944 us; speedup vs baseline: 1.2288x; 1.2288x over previous
//
#include <hip/hip_runtime.h>
#include <hip/hip_bf16.h>

// QDense: out = s * (U X U^H)[:128,:128] / tr + (1-s) * diag(softmax(rand_w))
// B=512, D=256, O=128.
// Round-5 = round-3 structure (best: 213us) + deep X-load pipeline:
//   - stage-A ks loop fully unrolled (loads hoisted -> ~3x in-flight bytes)
//   - __launch_bounds__(512,4) pins regs <=128 (keeps 16 waves/CU)
//   - f32->bf16 via v_cvt_pk_bf16_f32 (r4's proven VALU win)
// 1024 blocks (batch b = bx>>1, k'-half kh = bx&1), 512 thr.
// Stage A: Y[j, k'half] = X * U_half^H   (U_half staged in swizzled LDS)
// Stage B: sub[:, k'half] = U_sub * Y    (Y^T tile in swizzled LDS, U from global)
// Trace:   tr = trace(X * P), P = U_sub^H U_sub (prep), folded into stage A.

typedef __attribute__((ext_vector_type(4))) float f32x4;
typedef __attribute__((ext_vector_type(8))) short bf16x8;

static __device__ __forceinline__ short f2bf(float f) {   // prep kernels only
    unsigned u = __float_as_uint(f);
    u += 0x7fffu + ((u >> 16) & 1u);
    return (short)(u >> 16);
}

static __device__ __forceinline__ unsigned cvtpk2(float lo, float hi) {
    union { __hip_bfloat162 h; unsigned u; } c;
    c.h = __float22bfloat162_rn(float2{lo, hi});
    return c.u;
}

static __device__ __forceinline__ bf16x8 pack8(f32x4 a, f32x4 b) {
    union { unsigned u[4]; bf16x8 v; } r;
    r.u[0] = cvtpk2(a[0], a[1]);
    r.u[1] = cvtpk2(a[2], a[3]);
    r.u[2] = cvtpk2(b[0], b[1]);
    r.u[3] = cvtpk2(b[2], b[3]);
    return r.v;
}

static __device__ __forceinline__ f32x4 mfma16(bf16x8 a, bf16x8 b, f32x4 c) {
    return __builtin_amdgcn_mfma_f32_16x16x32_bf16(a, b, c, 0, 0, 0);
}

// ---- prep: convert U rows [0,128) to bf16 (weight is (D,D,2) interleaved) ----
__global__ void qprep_u(const float* __restrict__ wt,
                        short* __restrict__ Ur, short* __restrict__ Ui) {
    int idx = blockIdx.x * 256 + threadIdx.x;         // j*256+k, j<128
    float2 v = ((const float2*)wt)[idx];
    Ur[idx] = f2bf(v.x);
    Ui[idx] = f2bf(v.y);
}

// ---- prep: p = softmax(rand_w), s = sigmoid(lam) ----
__global__ void qprep_ps(const float* __restrict__ rw, const float* __restrict__ lm,
                         float* __restrict__ pv, float* __restrict__ sv) {
    int t = threadIdx.x;                               // 64 threads
    float w0 = rw[t], w1 = rw[t + 64];
    float m = fmaxf(w0, w1);
    #pragma unroll
    for (int o = 32; o > 0; o >>= 1) m = fmaxf(m, __shfl_xor(m, o));
    float e0 = expf(w0 - m), e1 = expf(w1 - m);
    float ss = e0 + e1;
    #pragma unroll
    for (int o = 32; o > 0; o >>= 1) ss += __shfl_xor(ss, o);
    pv[t] = e0 / ss;
    pv[t + 64] = e1 / ss;
    if (t == 0) sv[0] = 1.f / (1.f + expf(-lm[0]));
}

// ---- prep: Q[j][k] = P[k][j], P = U_sub^H U_sub (f32 source, bf16 out) ----
__global__ void qprep_q(const float* __restrict__ wt,
                        short* __restrict__ Qrb, short* __restrict__ Qib) {
    int j = blockIdx.x;          // 0..255
    int k = threadIdx.x;         // 0..255
    float ar = 0.f, ai = 0.f;
    for (int i = 0; i < 128; ++i) {
        float2 uk = ((const float2*)wt)[i * 256 + k];
        float2 uj = ((const float2*)wt)[i * 256 + j];
        ar += uk.x * uj.x + uk.y * uj.y;   // Re(conj(U[i,k]) U[i,j])
        ai += uk.x * uj.y - uk.y * uj.x;   // Im
    }
    Qrb[j * 256 + k] = f2bf(ar);
    Qib[j * 256 + k] = f2bf(ai);
}

// ---- main fused kernel ----
__global__ __launch_bounds__(512, 4) void qfused(
    const float* __restrict__ xr, const float* __restrict__ xi,
    const short* __restrict__ Urg, const short* __restrict__ Uig,
    const short* __restrict__ Qrb, const short* __restrict__ Qib,
    const float* __restrict__ pv, const float* __restrict__ sv,
    float* __restrict__ out)
{
    // LDS map (80 KB exactly -> 2 blocks/CU):
    // [0,32768):      UldsR  64 rows (k'half) x 512 B, XOR-swizzled
    // [32768,65536):  UldsI
    // [65536,73728):  YtR    64 rows (k'loc) x 128 B (64 j), XOR-swizzled
    // [73728,81920):  YtI    (reused as red[] in epilogue)
    __shared__ __align__(16) char smem[81920];

    const int bx   = blockIdx.x;
    const int b    = bx >> 1;
    const int kh   = bx & 1;
    const int tid  = threadIdx.x;
    const int lane = tid & 63;
    const int w    = tid >> 6;           // 0..7
    const int c16  = lane & 15;
    const int g4   = lane >> 4;          // 0..3

    // ---- stage U-half into swizzled LDS (source-slot permutation) ----
    #pragma unroll
    for (int q = 0; q < 4; ++q) {
        int c    = tid + q * 512;        // 0..2047 chunks of 16 B per plane
        int row  = c >> 5;               // 0..63
        int slot = c & 31;
        int ss   = slot ^ (row & 7);
        const short* sr = Urg + (size_t)(kh * 64 + row) * 256 + ss * 8;
        const short* si = Uig + (size_t)(kh * 64 + row) * 256 + ss * 8;
        *(bf16x8*)(smem + row * 512 + slot * 16)         = *(const bf16x8*)sr;
        *(bf16x8*)(smem + 32768 + row * 512 + slot * 16) = *(const bf16x8*)si;
    }
    __syncthreads();

    const float* xrb = xr + ((size_t)b << 16);
    const float* xib = xi + ((size_t)b << 16);

    const int  ja  = (w & 3) * 16;       // stage A j-row group within jt-step
    const int  kb  = (w >> 2) * 32;      // stage A k'-group
    const int  wm  = w >> 1;             // stage B i-quarter (0..3)
    const int  wn  = w & 1;              // stage B k'-half-of-half (0..1)
    const bool dotr = (w < 4);           // waves 0..3 own the trace

    f32x4 zero = {0.f, 0.f, 0.f, 0.f};
    f32x4 sR[2][2], sI[2][2];
    #pragma unroll
    for (int m = 0; m < 2; ++m)
        #pragma unroll
        for (int n = 0; n < 2; ++n) { sR[m][n] = zero; sI[m][n] = zero; }
    f32x4 tr4 = zero;

    for (int jt = 0; jt < 256; jt += 64) {
        // ---------- stage A: Yt[64 k'loc][64 j] for this jt-step ----------
        f32x4 yR[2], yI[2];
        yR[0] = zero; yR[1] = zero; yI[0] = zero; yI[1] = zero;

        const int jrow = jt + ja + c16;
        const float* xr_row = xrb + (size_t)jrow * 256 + g4 * 8;
        const float* xi_row = xib + (size_t)jrow * 256 + g4 * 8;
        const short* qr_row = Qrb + (size_t)jrow * 256 + g4 * 8;
        const short* qi_row = Qib + (size_t)jrow * 256 + g4 * 8;

        #pragma unroll
        for (int ks = 0; ks < 8; ++ks) {
            f32x4 a0 = *(const f32x4*)(xr_row + ks * 32);
            f32x4 a1 = *(const f32x4*)(xr_row + ks * 32 + 4);
            f32x4 b0 = *(const f32x4*)(xi_row + ks * 32);
            f32x4 b1 = *(const f32x4*)(xi_row + ks * 32 + 4);
            bf16x8 axr  = pack8(a0, a1);
            bf16x8 axi  = pack8(b0, b1);
            bf16x8 axrn = axr ^ (short)0x8000;

            #pragma unroll
            for (int nt = 0; nt < 2; ++nt) {
                int kloc = kb + nt * 16 + c16;
                int off  = kloc * 512 + ((ks * 64 + g4 * 16) ^ ((kloc & 7) << 4));
                bf16x8 bur = *(const bf16x8*)(smem + off);
                bf16x8 bui = *(const bf16x8*)(smem + 32768 + off);
                // Yr = Xr Ur^T + Xi Ui^T ; Yi = Xi Ur^T - Xr Ui^T
                yR[nt] = mfma16(axr,  bur, yR[nt]);
                yR[nt] = mfma16(axi,  bui, yR[nt]);
                yI[nt] = mfma16(axi,  bur, yI[nt]);
                yI[nt] = mfma16(axrn, bui, yI[nt]);
            }
            if (dotr) {
                bf16x8 bqr  = *(const bf16x8*)(qr_row + ks * 32);
                bf16x8 bqi  = *(const bf16x8*)(qi_row + ks * 32);
                bf16x8 axin = axi ^ (short)0x8000;
                // tr += Xr.Qr - Xi.Qi  (diag of D extracted at the end)
                tr4 = mfma16(axr,  bqr, tr4);
                tr4 = mfma16(axin, bqi, tr4);
            }
        }

        __syncthreads();   // previous stage-B Yt reads complete

        #pragma unroll
        for (int nt = 0; nt < 2; ++nt) {
            int kloc = kb + nt * 16 + c16;
            int off  = kloc * 128 + (((w & 3) * 32 + g4 * 8) ^ ((kloc & 7) << 4));
            uint2 vr, vi;
            vr.x = cvtpk2(yR[nt][0], yR[nt][1]);
            vr.y = cvtpk2(yR[nt][2], yR[nt][3]);
            vi.x = cvtpk2(yI[nt][0], yI[nt][1]);
            vi.y = cvtpk2(yI[nt][2], yI[nt][3]);
            *(uint2*)(smem + 65536 + off) = vr;
            *(uint2*)(smem + 73728 + off) = vi;
        }
        __syncthreads();

        // ---------- stage B: sub[:, kh-half] += U_sub[:, jt..jt+63] * Y ----------
        #pragma unroll
        for (int ks2 = 0; ks2 < 2; ++ks2) {
            bf16x8 aur[2], aui[2], auin[2];
            #pragma unroll
            for (int mt = 0; mt < 2; ++mt) {
                int i = wm * 32 + mt * 16 + c16;
                const short* pa = Urg + (size_t)i * 256 + jt + ks2 * 32 + g4 * 8;
                const short* pb = Uig + (size_t)i * 256 + jt + ks2 * 32 + g4 * 8;
                aur[mt]  = *(const bf16x8*)pa;
                aui[mt]  = *(const bf16x8*)pb;
                auin[mt] = aui[mt] ^ (short)0x8000;
            }
            #pragma unroll
            for (int nt2 = 0; nt2 < 2; ++nt2) {
                int kloc = wn * 32 + nt2 * 16 + c16;
                int off  = kloc * 128 + ((ks2 * 64 + g4 * 16) ^ ((kloc & 7) << 4));
                bf16x8 byr = *(const bf16x8*)(smem + 65536 + off);
                bf16x8 byi = *(const bf16x8*)(smem + 73728 + off);
                #pragma unroll
                for (int mt = 0; mt < 2; ++mt) {
                    // sub_r = Ur Yr - Ui Yi ; sub_i = Ui Yr + Ur Yi
                    sR[mt][nt2] = mfma16(aur[mt],  byr, sR[mt][nt2]);
                    sR[mt][nt2] = mfma16(auin[mt], byi, sR[mt][nt2]);
                    sI[mt][nt2] = mfma16(aui[mt],  byr, sI[mt][nt2]);
                    sI[mt][nt2] = mfma16(aur[mt],  byi, sI[mt][nt2]);
                }
            }
        }
    }

    // ---------- trace: extract diag of tr4 tile, reduce over block ----------
    float loc = (dotr && ((c16 >> 2) == g4)) ? tr4[c16 & 3] : 0.f;
    #pragma unroll
    for (int o = 32; o > 0; o >>= 1) loc += __shfl_xor(loc, o);
    __syncthreads();                       // Yt dead; reuse for reduction
    float* red = (float*)(smem + 65536);
    if (lane == 0) red[w] = loc;           // waves 4..7 contribute 0
    __syncthreads();
    float tr = red[0] + red[1] + red[2] + red[3] + red[4] + red[5] + red[6] + red[7];

    float s     = sv[0];
    float inv   = s / tr;
    float onems = 1.f - s;
    float* outr = out + (size_t)b * 16384;
    float* outi = out + 8388608 + (size_t)b * 16384;

    #pragma unroll
    for (int mt = 0; mt < 2; ++mt)
        #pragma unroll
        for (int nt2 = 0; nt2 < 2; ++nt2) {
            int colc = kh * 64 + wn * 32 + nt2 * 16 + c16;
            #pragma unroll
            for (int r = 0; r < 4; ++r) {
                int row = wm * 32 + mt * 16 + g4 * 4 + r;
                float vr = sR[mt][nt2][r] * inv;
                if (row == colc) vr += onems * pv[row];
                outr[row * 128 + colc] = vr;
                outi[row * 128 + colc] = sI[mt][nt2][r] * inv;
            }
        }
}

extern "C" void kernel_launch(void* const* d_in, const int* in_sizes, int n_in,
                              void* d_out, int out_size, void* d_ws, size_t ws_size,
                              hipStream_t stream) {
    (void)in_sizes; (void)n_in; (void)out_size; (void)ws_size;
    const float* xr = (const float*)d_in[0];
    const float* xi = (const float*)d_in[1];
    const float* wt = (const float*)d_in[2];
    const float* rw = (const float*)d_in[3];
    const float* lm = (const float*)d_in[4];

    short* Ur  = (short*)d_ws;                        // 128x256 bf16 (64 KB)
    short* Ui  = Ur + 32768;                          // 64 KB
    float* pv  = (float*)((char*)d_ws + 131072);      // 128 f32
    float* sv  = pv + 128;                            // 1 f32
    short* Qrb = (short*)((char*)d_ws + 135168);      // 256x256 bf16 (128 KB)
    short* Qib = (short*)((char*)d_ws + 266240);      // 128 KB
    float* o   = (float*)d_out;

    qprep_u<<<dim3(128), dim3(256), 0, stream>>>(wt, Ur, Ui);
    qprep_ps<<<dim3(1), dim3(64), 0, stream>>>(rw, lm, pv, sv);
    qprep_q<<<dim3(256), dim3(256), 0, stream>>>(wt, Qrb, Qib);
    qfused<<<dim3(1024), dim3(512), 0, stream>>>(xr, xi, Ur, Ui, Qrb, Qib, pv, sv, o);
}